// Round 15
// baseline (361.930 us; speedup 1.0000x reference)
//
#include <hip/hip_runtime.h>
#include <hip/hip_cooperative_groups.h>
#include <cstdint>

namespace cg = cooperative_groups;

#define NPTS   16384
#define BATCH  4
#define BNP    65536
#define CIN    64
#define KNB    16
#define COUT   128
#define BN_EPS 1e-5f

typedef __attribute__((ext_vector_type(8))) short     short8;
typedef __attribute__((ext_vector_type(4))) float     f32x4;
typedef __attribute__((ext_vector_type(2))) unsigned  u32x2;
typedef __attribute__((ext_vector_type(4))) int       i32x4;

__device__ __forceinline__ unsigned short f2bf(float f) {   // RNE
    unsigned u = __float_as_uint(f);
    u += 0x7FFFu + ((u >> 16) & 1u);
    return (unsigned short)(u >> 16);
}
__device__ __forceinline__ float bf2f(unsigned short h) {
    return __uint_as_float(((unsigned)h) << 16);
}

// ================= FUSED cooperative kernel: prep | main | part | apply ================
// R14 lesson: fusing BN partials into k_main's registers costs +18us (codegen+tail) --
// reverted; stats via the deterministic k_part pass, now a PHASE after grid.sync.
// Rationale: across R7/R8/R10/R14, total ~= k_main + 95-100us while the 3 aux kernels'
// memory cost is ~28us -> ~70us is launch/graph overhead. One cooperative launch with
// 3 grid syncs removes it. Grid 512x256 (2 blocks/CU co-resident: regs in (128,256]
// bracket, 36KB LDS/block). Main phase = R10 pair-ILP body, 2 groups/wave (R7-proven).
__global__ __launch_bounds__(256, 2) void k_fused(
    const float* __restrict__ feat, const int* __restrict__ nidx,
    const float* __restrict__ Wm,   const float* __restrict__ Wc,
    const float* __restrict__ gamma, const float* __restrict__ beta,
    float* __restrict__ out, unsigned short* __restrict__ fb,
    unsigned short* __restrict__ wmb, unsigned short* __restrict__ wcb,
    float* __restrict__ part)
{
    __shared__ float tl[CIN][CIN + 1];                         // prep (16.6 KB)
    __shared__ __align__(16) unsigned short plds[4][2][1152];  // main (18.4 KB)
    __shared__ float sc[COUT], sh[COUT];                       // apply (1 KB)
    __shared__ float ls[4], lq[4];                             // part

    const int tid  = threadIdx.x;
    const int wv   = tid >> 6;
    const int lane = tid & 63;

    // ===== Phase P: feature [B][C][N] -> flat bf16 [B*N][64]; blk 0: weight cvt =====
    {
        #pragma clang loop unroll(disable)
        for (int t2 = 0; t2 < 2; ++t2) {
            int blk = blockIdx.x * 2 + t2;                     // 1024 tiles / 512 blocks
            int b = blk >> 8, n0 = (blk & 255) << 6;
            const float* fp = feat + (size_t)b * CIN * NPTS;
            #pragma unroll
            for (int r = 0; r < CIN; r += 4) {
                int c = r + wv;
                tl[c][lane] = fp[(size_t)c * NPTS + n0 + lane];   // coalesced along n
            }
            __syncthreads();
            unsigned short* ob = fb + (size_t)(b * NPTS + n0) * CIN;
            #pragma unroll
            for (int r = 0; r < CIN; r += 4) {
                int x = r + wv;
                ob[(size_t)x * CIN + lane] = f2bf(tl[lane][x]);
            }
            __syncthreads();                                   // tl reused next trip
        }
        if (blockIdx.x == 0) {
            for (int i = tid; i < CIN * CIN; i += 256)  wmb[i] = f2bf(Wm[i]);
            for (int i = tid; i < COUT * CIN; i += 256) wcb[i] = f2bf(Wc[i]);
        }
    }
    cg::this_grid().sync();

    // ===== Phase M: gather+attention+linear (R10 pair-ILP body, 2 groups/wave) =====
    {
        const int ptc = lane & 15;
        const int qg  = lane >> 4;
        const int p4  = ptc * 4;

        short8 wmF[4][2];
        #pragma unroll
        for (int mt = 0; mt < 4; ++mt)
            #pragma unroll
            for (int ks = 0; ks < 2; ++ks)
                wmF[mt][ks] = *(const short8*)&wmb[(size_t)(mt * 16 + ptc) * CIN + qg * 8 + ks * 32];
        short8 wcF[8][2];
        #pragma unroll
        for (int mt = 0; mt < 8; ++mt)
            #pragma unroll
            for (int ks = 0; ks < 2; ++ks)
                wcF[mt][ks] = *(const short8*)&wcb[(size_t)(mt * 16 + ptc) * CIN + qg * 8 + ks * 32];

        f32x4 acc2[8];
        #pragma unroll
        for (int i = 0; i < 8; ++i) acc2[i] = (f32x4){0.f, 0.f, 0.f, 0.f};

        for (int g = blockIdx.x * 4 + wv; g < BNP / KNB; g += 2048) {   // 2 trips
            i32x4 iv = *(const i32x4*)(nidx + (size_t)g * 256 + lane * 4);

            short8 rb0[4], rb1[4];
            u32x2  svr[4][4];
            int    rid[4];
            #pragma unroll
            for (int kk = 0; kk < 4; ++kk) {
                int id = __shfl(iv[kk], p4);                   // idx[ptc][kk], kk<4
                rid[kk] = id;
                const unsigned short* gp = fb + (size_t)id * CIN;
                rb0[kk] = *(const short8*)(gp + qg * 8);
                rb1[kk] = *(const short8*)(gp + 32 + qg * 8);
                #pragma unroll
                for (int mt = 0; mt < 4; ++mt)
                    svr[kk][mt] = *(const u32x2*)(gp + mt * 16 + qg * 4);
            }

            #pragma unroll
            for (int p = 0; p < 8; ++p) {                      // pair (2p, 2p+1)
                const int sA = (2 * p) & 3;
                const int sB = sA + 1;

                f32x4 zero4 = (f32x4){0.f, 0.f, 0.f, 0.f};
                f32x4 a1A[4], a1B[4];
                #pragma unroll
                for (int mt = 0; mt < 4; ++mt) {
                    f32x4 t0 = __builtin_amdgcn_mfma_f32_16x16x32_bf16(wmF[mt][0], rb0[sA], zero4, 0, 0, 0);
                    a1A[mt]  = __builtin_amdgcn_mfma_f32_16x16x32_bf16(wmF[mt][1], rb1[sA], t0,    0, 0, 0);
                }
                #pragma unroll
                for (int mt = 0; mt < 4; ++mt) {
                    f32x4 t0 = __builtin_amdgcn_mfma_f32_16x16x32_bf16(wmF[mt][0], rb0[sB], zero4, 0, 0, 0);
                    a1B[mt]  = __builtin_amdgcn_mfma_f32_16x16x32_bf16(wmF[mt][1], rb1[sB], t0,    0, 0, 0);
                }

                if (p < 6) {
                    int idA = __shfl(iv[sA], p4 + ((2 * p + 4) >> 2));
                    int idB = __shfl(iv[sB], p4 + ((2 * p + 5) >> 2));
                    rid[sA] = idA;
                    rid[sB] = idB;
                    const unsigned short* gA = fb + (size_t)idA * CIN;
                    const unsigned short* gB = fb + (size_t)idB * CIN;
                    rb0[sA] = *(const short8*)(gA + qg * 8);
                    rb1[sA] = *(const short8*)(gA + 32 + qg * 8);
                    rb0[sB] = *(const short8*)(gB + qg * 8);
                    rb1[sB] = *(const short8*)(gB + 32 + qg * 8);
                }

                float ssA = 0.f, ssB = 0.f;
                #pragma unroll
                for (int mt = 0; mt < 4; ++mt)
                    #pragma unroll
                    for (int r = 0; r < 4; ++r) {
                        float xA = __expf(a1A[mt][r]);
                        float xB = __expf(a1B[mt][r]);
                        a1A[mt][r] = xA;  ssA += xA;
                        a1B[mt][r] = xB;  ssB += xB;
                    }
                ssA += __shfl_xor(ssA, 16);
                ssB += __shfl_xor(ssB, 16);
                ssA += __shfl_xor(ssA, 32);
                ssB += __shfl_xor(ssB, 32);
                float invA = __builtin_amdgcn_rcpf(ssA);
                float invB = __builtin_amdgcn_rcpf(ssB);

                #pragma unroll
                for (int mt = 0; mt < 4; ++mt) {
                    u32x2 svA = svr[sA][mt], svB = svr[sB][mt];
                    unsigned loA = svA[0], hiA = svA[1];
                    unsigned loB = svB[0], hiB = svB[1];
                    float pA0 = bf2f((unsigned short)loA)         * (a1A[mt][0] * invA);
                    float pA1 = bf2f((unsigned short)(loA >> 16)) * (a1A[mt][1] * invA);
                    float pA2 = bf2f((unsigned short)hiA)         * (a1A[mt][2] * invA);
                    float pA3 = bf2f((unsigned short)(hiA >> 16)) * (a1A[mt][3] * invA);
                    float pB0 = bf2f((unsigned short)loB)         * (a1B[mt][0] * invB);
                    float pB1 = bf2f((unsigned short)(loB >> 16)) * (a1B[mt][1] * invB);
                    float pB2 = bf2f((unsigned short)hiB)         * (a1B[mt][2] * invB);
                    float pB3 = bf2f((unsigned short)(hiB >> 16)) * (a1B[mt][3] * invB);
                    unsigned wA0 = ((__float_as_uint(pA0) + 0x8000u) >> 16) |
                                   ((__float_as_uint(pA1) + 0x8000u) & 0xFFFF0000u);
                    unsigned wA1 = ((__float_as_uint(pA2) + 0x8000u) >> 16) |
                                   ((__float_as_uint(pA3) + 0x8000u) & 0xFFFF0000u);
                    unsigned wB0 = ((__float_as_uint(pB0) + 0x8000u) >> 16) |
                                   ((__float_as_uint(pB1) + 0x8000u) & 0xFFFF0000u);
                    unsigned wB1 = ((__float_as_uint(pB2) + 0x8000u) >> 16) |
                                   ((__float_as_uint(pB3) + 0x8000u) & 0xFFFF0000u);
                    *(u32x2*)&plds[wv][0][ptc * 72 + mt * 16 + qg * 4] = (u32x2){wA0, wA1};
                    *(u32x2*)&plds[wv][1][ptc * 72 + mt * 16 + qg * 4] = (u32x2){wB0, wB1};
                }

                if (p < 6) {
                    const unsigned short* gA = fb + (size_t)rid[sA] * CIN;
                    const unsigned short* gB = fb + (size_t)rid[sB] * CIN;
                    #pragma unroll
                    for (int mt = 0; mt < 4; ++mt) {
                        svr[sA][mt] = *(const u32x2*)(gA + mt * 16 + qg * 4);
                        svr[sB][mt] = *(const u32x2*)(gB + mt * 16 + qg * 4);
                    }
                }

                short8 b2A0 = *(const short8*)&plds[wv][0][ptc * 72 +      qg * 8];
                short8 b2A1 = *(const short8*)&plds[wv][0][ptc * 72 + 32 + qg * 8];
                short8 b2B0 = *(const short8*)&plds[wv][1][ptc * 72 +      qg * 8];
                short8 b2B1 = *(const short8*)&plds[wv][1][ptc * 72 + 32 + qg * 8];

                #pragma unroll
                for (int mt = 0; mt < 8; ++mt) {
                    acc2[mt] = __builtin_amdgcn_mfma_f32_16x16x32_bf16(wcF[mt][0], b2A0, acc2[mt], 0, 0, 0);
                    acc2[mt] = __builtin_amdgcn_mfma_f32_16x16x32_bf16(wcF[mt][1], b2A1, acc2[mt], 0, 0, 0);
                }
                #pragma unroll
                for (int mt = 0; mt < 8; ++mt) {
                    acc2[mt] = __builtin_amdgcn_mfma_f32_16x16x32_bf16(wcF[mt][0], b2B0, acc2[mt], 0, 0, 0);
                    acc2[mt] = __builtin_amdgcn_mfma_f32_16x16x32_bf16(wcF[mt][1], b2B1, acc2[mt], 0, 0, 0);
                }
            }

            // epilogue: direct C-layout store; reset acc2 for next group
            int p0 = g * KNB;
            int b  = p0 >> 14;
            int nn = (p0 & (NPTS - 1)) + ptc;
            float* ob = out + (((size_t)b * COUT) << 14) + nn;
            #pragma unroll
            for (int mt = 0; mt < 8; ++mt)
                #pragma unroll
                for (int r = 0; r < 4; ++r) {
                    ob[((size_t)(mt * 16 + qg * 4 + r)) << 14] = acc2[mt][r];
                    acc2[mt][r] = 0.f;
                }
        }
    }
    cg::this_grid().sync();

    // ===== Phase R: deterministic BN partials, block = (o, b) (k_part verbatim) =====
    {
        int o = blockIdx.x >> 2, b = blockIdx.x & 3;
        const float4* pp = (const float4*)(out + (((size_t)(b * COUT + o)) << 14));
        float s = 0.f, q = 0.f;
        for (int i = tid; i < NPTS / 4; i += 256) {
            float4 v = pp[i];
            s += (v.x + v.y) + (v.z + v.w);
            q += (v.x * v.x + v.y * v.y) + (v.z * v.z + v.w * v.w);
        }
        #pragma unroll
        for (int off = 32; off >= 1; off >>= 1) {
            s += __shfl_xor(s, off);
            q += __shfl_xor(q, off);
        }
        if (lane == 0) { ls[wv] = s; lq[wv] = q; }
        __syncthreads();
        if (tid == 0) {
            part[blockIdx.x * 2]     = (ls[0] + ls[1]) + (ls[2] + ls[3]);
            part[blockIdx.x * 2 + 1] = (lq[0] + lq[1]) + (lq[2] + lq[3]);
        }
    }
    cg::this_grid().sync();

    // ===== Phase A: finalize stats + apply BN in place (k_apply, grid 512) =====
    {
        if (tid < COUT) {
            float s = 0.f, q = 0.f;
            #pragma unroll
            for (int j = 0; j < 4; ++j) {
                s += part[(tid * 4 + j) * 2];
                q += part[(tid * 4 + j) * 2 + 1];
            }
            float mean = s * (1.0f / BNP);
            float var  = q * (1.0f / BNP) - mean * mean;
            float a = gamma[tid] * rsqrtf(var + BN_EPS);
            sc[tid] = a; sh[tid] = beta[tid] - mean * a;
        }
        __syncthreads();
        const int total4 = BATCH * COUT * NPTS / 4;
        for (long i = (long)blockIdx.x * 256 + tid; i < total4; i += (long)gridDim.x * 256) {
            int ch = ((int)(i >> 12)) & 127;
            float4 v = ((float4*)out)[i];
            float a = sc[ch], b2 = sh[ch];
            v.x = fmaf(v.x, a, b2); v.y = fmaf(v.y, a, b2);
            v.z = fmaf(v.z, a, b2); v.w = fmaf(v.w, a, b2);
            ((float4*)out)[i] = v;
        }
    }
}

// ================= Fallback path: R10's proven 4-kernel pipeline (165.5us) =============
__global__ __launch_bounds__(256) void k_prep(const float* __restrict__ feat,
                                              unsigned short* __restrict__ fb,
                                              const float* __restrict__ Wm,
                                              const float* __restrict__ Wc,
                                              unsigned short* __restrict__ wmb,
                                              unsigned short* __restrict__ wcb)
{
    if (blockIdx.x == 1024) {
        #pragma unroll
        for (int i = threadIdx.x; i < CIN * CIN; i += 256)       wmb[i] = f2bf(Wm[i]);
        #pragma unroll
        for (int i = threadIdx.x; i < COUT * CIN; i += 256)      wcb[i] = f2bf(Wc[i]);
        return;
    }
    __shared__ float t[CIN][CIN + 1];
    int blk = blockIdx.x;
    int b   = blk >> 8;
    int n0  = (blk & 255) << 6;
    int sub = threadIdx.x >> 6, lane = threadIdx.x & 63;
    const float* fp = feat + (size_t)b * CIN * NPTS;
    #pragma unroll
    for (int r = 0; r < CIN; r += 4) {
        int c = r + sub;
        t[c][lane] = fp[(size_t)c * NPTS + n0 + lane];
    }
    __syncthreads();
    unsigned short* ob = fb + (size_t)(b * NPTS + n0) * CIN;
    #pragma unroll
    for (int r = 0; r < CIN; r += 4) {
        int x = r + sub;
        ob[(size_t)x * CIN + lane] = f2bf(t[lane][x]);
    }
}

__global__ __launch_bounds__(256, 2) void k_main(
    const unsigned short* __restrict__ fb, const int* __restrict__ nidx,
    const unsigned short* __restrict__ wmb, const unsigned short* __restrict__ wcb,
    float* __restrict__ out)
{
    __shared__ __align__(16) unsigned short plds[4][2][1152];
    const int tid  = threadIdx.x;
    const int wv   = tid >> 6;
    const int lane = tid & 63;
    const int ptc  = lane & 15;
    const int qg   = lane >> 4;
    const int p4   = ptc * 4;

    short8 wmF[4][2];
    #pragma unroll
    for (int mt = 0; mt < 4; ++mt)
        #pragma unroll
        for (int ks = 0; ks < 2; ++ks)
            wmF[mt][ks] = *(const short8*)&wmb[(size_t)(mt * 16 + ptc) * CIN + qg * 8 + ks * 32];
    short8 wcF[8][2];
    #pragma unroll
    for (int mt = 0; mt < 8; ++mt)
        #pragma unroll
        for (int ks = 0; ks < 2; ++ks)
            wcF[mt][ks] = *(const short8*)&wcb[(size_t)(mt * 16 + ptc) * CIN + qg * 8 + ks * 32];

    f32x4 acc2[8];
    #pragma unroll
    for (int i = 0; i < 8; ++i) acc2[i] = (f32x4){0.f, 0.f, 0.f, 0.f};

    const int g = blockIdx.x * 4 + wv;
    i32x4 iv = *(const i32x4*)(nidx + (size_t)g * 256 + lane * 4);

    short8 rb0[4], rb1[4];
    u32x2  svr[4][4];
    int    rid[4];
    #pragma unroll
    for (int kk = 0; kk < 4; ++kk) {
        int id = __shfl(iv[kk], p4);
        rid[kk] = id;
        const unsigned short* gp = fb + (size_t)id * CIN;
        rb0[kk] = *(const short8*)(gp + qg * 8);
        rb1[kk] = *(const short8*)(gp + 32 + qg * 8);
        #pragma unroll
        for (int mt = 0; mt < 4; ++mt)
            svr[kk][mt] = *(const u32x2*)(gp + mt * 16 + qg * 4);
    }

    #pragma unroll
    for (int p = 0; p < 8; ++p) {
        const int sA = (2 * p) & 3;
        const int sB = sA + 1;
        f32x4 zero4 = (f32x4){0.f, 0.f, 0.f, 0.f};
        f32x4 a1A[4], a1B[4];
        #pragma unroll
        for (int mt = 0; mt < 4; ++mt) {
            f32x4 t0 = __builtin_amdgcn_mfma_f32_16x16x32_bf16(wmF[mt][0], rb0[sA], zero4, 0, 0, 0);
            a1A[mt]  = __builtin_amdgcn_mfma_f32_16x16x32_bf16(wmF[mt][1], rb1[sA], t0,    0, 0, 0);
        }
        #pragma unroll
        for (int mt = 0; mt < 4; ++mt) {
            f32x4 t0 = __builtin_amdgcn_mfma_f32_16x16x32_bf16(wmF[mt][0], rb0[sB], zero4, 0, 0, 0);
            a1B[mt]  = __builtin_amdgcn_mfma_f32_16x16x32_bf16(wmF[mt][1], rb1[sB], t0,    0, 0, 0);
        }
        if (p < 6) {
            int idA = __shfl(iv[sA], p4 + ((2 * p + 4) >> 2));
            int idB = __shfl(iv[sB], p4 + ((2 * p + 5) >> 2));
            rid[sA] = idA;
            rid[sB] = idB;
            const unsigned short* gA = fb + (size_t)idA * CIN;
            const unsigned short* gB = fb + (size_t)idB * CIN;
            rb0[sA] = *(const short8*)(gA + qg * 8);
            rb1[sA] = *(const short8*)(gA + 32 + qg * 8);
            rb0[sB] = *(const short8*)(gB + qg * 8);
            rb1[sB] = *(const short8*)(gB + 32 + qg * 8);
        }
        float ssA = 0.f, ssB = 0.f;
        #pragma unroll
        for (int mt = 0; mt < 4; ++mt)
            #pragma unroll
            for (int r = 0; r < 4; ++r) {
                float xA = __expf(a1A[mt][r]);
                float xB = __expf(a1B[mt][r]);
                a1A[mt][r] = xA;  ssA += xA;
                a1B[mt][r] = xB;  ssB += xB;
            }
        ssA += __shfl_xor(ssA, 16);
        ssB += __shfl_xor(ssB, 16);
        ssA += __shfl_xor(ssA, 32);
        ssB += __shfl_xor(ssB, 32);
        float invA = __builtin_amdgcn_rcpf(ssA);
        float invB = __builtin_amdgcn_rcpf(ssB);
        #pragma unroll
        for (int mt = 0; mt < 4; ++mt) {
            u32x2 svA = svr[sA][mt], svB = svr[sB][mt];
            unsigned loA = svA[0], hiA = svA[1];
            unsigned loB = svB[0], hiB = svB[1];
            float pA0 = bf2f((unsigned short)loA)         * (a1A[mt][0] * invA);
            float pA1 = bf2f((unsigned short)(loA >> 16)) * (a1A[mt][1] * invA);
            float pA2 = bf2f((unsigned short)hiA)         * (a1A[mt][2] * invA);
            float pA3 = bf2f((unsigned short)(hiA >> 16)) * (a1A[mt][3] * invA);
            float pB0 = bf2f((unsigned short)loB)         * (a1B[mt][0] * invB);
            float pB1 = bf2f((unsigned short)(loB >> 16)) * (a1B[mt][1] * invB);
            float pB2 = bf2f((unsigned short)hiB)         * (a1B[mt][2] * invB);
            float pB3 = bf2f((unsigned short)(hiB >> 16)) * (a1B[mt][3] * invB);
            unsigned wA0 = ((__float_as_uint(pA0) + 0x8000u) >> 16) |
                           ((__float_as_uint(pA1) + 0x8000u) & 0xFFFF0000u);
            unsigned wA1 = ((__float_as_uint(pA2) + 0x8000u) >> 16) |
                           ((__float_as_uint(pA3) + 0x8000u) & 0xFFFF0000u);
            unsigned wB0 = ((__float_as_uint(pB0) + 0x8000u) >> 16) |
                           ((__float_as_uint(pB1) + 0x8000u) & 0xFFFF0000u);
            unsigned wB1 = ((__float_as_uint(pB2) + 0x8000u) >> 16) |
                           ((__float_as_uint(pB3) + 0x8000u) & 0xFFFF0000u);
            *(u32x2*)&plds[wv][0][ptc * 72 + mt * 16 + qg * 4] = (u32x2){wA0, wA1};
            *(u32x2*)&plds[wv][1][ptc * 72 + mt * 16 + qg * 4] = (u32x2){wB0, wB1};
        }
        if (p < 6) {
            const unsigned short* gA = fb + (size_t)rid[sA] * CIN;
            const unsigned short* gB = fb + (size_t)rid[sB] * CIN;
            #pragma unroll
            for (int mt = 0; mt < 4; ++mt) {
                svr[sA][mt] = *(const u32x2*)(gA + mt * 16 + qg * 4);
                svr[sB][mt] = *(const u32x2*)(gB + mt * 16 + qg * 4);
            }
        }
        short8 b2A0 = *(const short8*)&plds[wv][0][ptc * 72 +      qg * 8];
        short8 b2A1 = *(const short8*)&plds[wv][0][ptc * 72 + 32 + qg * 8];
        short8 b2B0 = *(const short8*)&plds[wv][1][ptc * 72 +      qg * 8];
        short8 b2B1 = *(const short8*)&plds[wv][1][ptc * 72 + 32 + qg * 8];
        #pragma unroll
        for (int mt = 0; mt < 8; ++mt) {
            acc2[mt] = __builtin_amdgcn_mfma_f32_16x16x32_bf16(wcF[mt][0], b2A0, acc2[mt], 0, 0, 0);
            acc2[mt] = __builtin_amdgcn_mfma_f32_16x16x32_bf16(wcF[mt][1], b2A1, acc2[mt], 0, 0, 0);
        }
        #pragma unroll
        for (int mt = 0; mt < 8; ++mt) {
            acc2[mt] = __builtin_amdgcn_mfma_f32_16x16x32_bf16(wcF[mt][0], b2B0, acc2[mt], 0, 0, 0);
            acc2[mt] = __builtin_amdgcn_mfma_f32_16x16x32_bf16(wcF[mt][1], b2B1, acc2[mt], 0, 0, 0);
        }
    }

    int p0 = g * KNB;
    int b  = p0 >> 14;
    int nn = (p0 & (NPTS - 1)) + ptc;
    float* ob = out + (((size_t)b * COUT) << 14) + nn;
    #pragma unroll
    for (int mt = 0; mt < 8; ++mt)
        #pragma unroll
        for (int r = 0; r < 4; ++r)
            ob[((size_t)(mt * 16 + qg * 4 + r)) << 14] = acc2[mt][r];
}

__global__ __launch_bounds__(256) void k_part(const float* __restrict__ out,
                                              float* __restrict__ part)
{
    int o = blockIdx.x >> 2, b = blockIdx.x & 3;
    const float4* p = (const float4*)(out + (((size_t)(b * COUT + o)) << 14));
    float s = 0.f, q = 0.f;
    for (int i = threadIdx.x; i < NPTS / 4; i += 256) {
        float4 v = p[i];
        s += (v.x + v.y) + (v.z + v.w);
        q += (v.x * v.x + v.y * v.y) + (v.z * v.z + v.w * v.w);
    }
    #pragma unroll
    for (int off = 32; off >= 1; off >>= 1) {
        s += __shfl_xor(s, off);
        q += __shfl_xor(q, off);
    }
    __shared__ float ls[4], lq[4];
    if ((threadIdx.x & 63) == 0) { ls[threadIdx.x >> 6] = s; lq[threadIdx.x >> 6] = q; }
    __syncthreads();
    if (threadIdx.x == 0) {
        part[blockIdx.x * 2]     = (ls[0] + ls[1]) + (ls[2] + ls[3]);
        part[blockIdx.x * 2 + 1] = (lq[0] + lq[1]) + (lq[2] + lq[3]);
    }
}

__global__ __launch_bounds__(256) void k_apply(float* __restrict__ out,
                                               const float* __restrict__ part,
                                               const float* __restrict__ gamma,
                                               const float* __restrict__ beta)
{
    __shared__ float sc[COUT], sh[COUT];
    int t = threadIdx.x;
    if (t < COUT) {
        float s = 0.f, q = 0.f;
        #pragma unroll
        for (int j = 0; j < 4; ++j) {
            s += part[(t * 4 + j) * 2];
            q += part[(t * 4 + j) * 2 + 1];
        }
        float mean = s * (1.0f / BNP);
        float var  = q * (1.0f / BNP) - mean * mean;
        float a = gamma[t] * rsqrtf(var + BN_EPS);
        sc[t] = a; sh[t] = beta[t] - mean * a;
    }
    __syncthreads();
    const int total4 = BATCH * COUT * NPTS / 4;
    for (long i = (long)blockIdx.x * 256 + t; i < total4; i += (long)gridDim.x * 256) {
        int ch = ((int)(i >> 12)) & 127;
        float4 v = ((float4*)out)[i];
        float a = sc[ch], b2 = sh[ch];
        v.x = fmaf(v.x, a, b2); v.y = fmaf(v.y, a, b2);
        v.z = fmaf(v.z, a, b2); v.w = fmaf(v.w, a, b2);
        ((float4*)out)[i] = v;
    }
}

extern "C" void kernel_launch(void* const* d_in, const int* in_sizes, int n_in,
                              void* d_out, int out_size, void* d_ws, size_t ws_size,
                              hipStream_t stream)
{
    const float* feat  = (const float*)d_in[0];
    const int*   nidx  = (const int*)  d_in[1];
    // d_in[2] = permatrix (unused); d_in[5] = b_conv (exactly absorbed by BN)
    const float* Wm    = (const float*)d_in[3];
    const float* Wc    = (const float*)d_in[4];
    const float* gamma = (const float*)d_in[6];
    const float* beta  = (const float*)d_in[7];
    float* out = (float*)d_out;

    char* ws = (char*)d_ws;
    unsigned short* fb   = (unsigned short*)ws;                       // 8.39 MB
    float*          part = (float*)(ws + (size_t)BNP * CIN * 2);      // 4 KB
    unsigned short* wmb  = (unsigned short*)(ws + (size_t)BNP * CIN * 2 + 4096);
    unsigned short* wcb  = wmb + CIN * CIN;                           // 8 KB + 16 KB

    void* args[] = {
        (void*)&feat, (void*)&nidx, (void*)&Wm, (void*)&Wc,
        (void*)&gamma, (void*)&beta, (void*)&out,
        (void*)&fb, (void*)&wmb, (void*)&wcb, (void*)&part
    };
    hipError_t e = hipLaunchCooperativeKernel((const void*)k_fused,
                                              dim3(512), dim3(256), args, 0, stream);
    if (e != hipSuccess) {
        (void)hipGetLastError();                  // clear; fall back to 4-kernel path
        k_prep <<<1025, 256, 0, stream>>>(feat, fb, Wm, Wc, wmb, wcb);
        k_main <<<1024, 256, 0, stream>>>(fb, nidx, wmb, wcb, out);
        k_part <<<512,  256, 0, stream>>>(out, part);
        k_apply<<<2048, 256, 0, stream>>>(out, part, gamma, beta);
    }
}

// Round 16
// 161.487 us; speedup vs baseline: 2.2412x; 2.2412x over previous
//
#include <hip/hip_runtime.h>
#include <cstdint>

#define NPTS   16384
#define BATCH  4
#define BNP    65536
#define CIN    64
#define KNB    16
#define COUT   128
#define BN_EPS 1e-5f

typedef __attribute__((ext_vector_type(8))) short     short8;
typedef __attribute__((ext_vector_type(4))) float     f32x4;
typedef __attribute__((ext_vector_type(2))) unsigned  u32x2;
typedef __attribute__((ext_vector_type(4))) int       i32x4;

__device__ __forceinline__ unsigned short f2bf(float f) {   // RNE
    unsigned u = __float_as_uint(f);
    u += 0x7FFFu + ((u >> 16) & 1u);
    return (unsigned short)(u >> 16);
}
__device__ __forceinline__ float bf2f(unsigned short h) {
    return __uint_as_float(((unsigned)h) << 16);
}

// ---- K0: feature [B][C][N] -> flat bf16 [B*N][64]; blk 1024: weight cvt ----
// R16: read side vectorized (float4, 16B/lane, 4 loads/thread vs 16 scalar).
// LDS-write banks: lane(c=t>>2,q=t&3) base = c*65 + q*16 words -> 2-way max (free).
// Transpose write side unchanged (t[lane][x], stride 65, conflict-free).
__global__ __launch_bounds__(256) void k_prep(const float* __restrict__ feat,
                                              unsigned short* __restrict__ fb,
                                              const float* __restrict__ Wm,
                                              const float* __restrict__ Wc,
                                              unsigned short* __restrict__ wmb,
                                              unsigned short* __restrict__ wcb)
{
    if (blockIdx.x == 1024) {           // aux block: bf16-ify weights
        #pragma unroll
        for (int i = threadIdx.x; i < CIN * CIN; i += 256)       wmb[i] = f2bf(Wm[i]);
        #pragma unroll
        for (int i = threadIdx.x; i < COUT * CIN; i += 256)      wcb[i] = f2bf(Wc[i]);
        return;
    }
    __shared__ float t[CIN][CIN + 1];
    int blk = blockIdx.x;
    int b   = blk >> 8;
    int n0  = (blk & 255) << 6;
    int c   = threadIdx.x >> 2;                            // 0..63: source channel row
    int q   = threadIdx.x & 3;                             // quarter of the 64-pt row
    const float* fp = feat + (size_t)b * CIN * NPTS + (size_t)c * NPTS + n0 + q * 16;
    #pragma unroll
    for (int j = 0; j < 4; ++j) {
        float4 v = *(const float4*)(fp + j * 4);
        int o = q * 16 + j * 4;
        t[c][o]     = v.x;
        t[c][o + 1] = v.y;
        t[c][o + 2] = v.z;
        t[c][o + 3] = v.w;
    }
    __syncthreads();
    int sub = threadIdx.x >> 6, lane = threadIdx.x & 63;
    unsigned short* ob = fb + (size_t)(b * NPTS + n0) * CIN;
    #pragma unroll
    for (int r = 0; r < CIN; r += 4) {
        int x = r + sub;
        ob[(size_t)x * CIN + lane] = f2bf(t[lane][x]);     // row n0+x, ch=lane
    }
}

// ---------------- K1: gather+attention+linear -- R7 VERBATIM (proven 65.4us) -----------
// Best-measured config: grid 512, 2 groups/wave, 3-deep register rings, VGPR 116.
// R15 coop-fusion regressed 4x (device-coherent mode defeats fb caching) -- reverted.
// Do NOT touch: pool-first (R2/4 spill trap), global_load_lds (R5 vmcnt drain),
// grid 1024 (R8 no-op: register-capped at 2 waves/SIMD), k-pair ILP (R10 no-op).
__global__ __launch_bounds__(256, 2) void k_main(
    const unsigned short* __restrict__ fb,   // [BNP][64] bf16
    const int* __restrict__ nidx,            // [BNP][16]
    const unsigned short* __restrict__ wmb,  // [64][64] bf16
    const unsigned short* __restrict__ wcb,  // [128][64] bf16
    float* __restrict__ out)                 // [4][128][16384], pre-BN
{
    __shared__ __align__(16) unsigned short plds[4][1152];   // 9.2 KB, wave-private

    const int tid  = threadIdx.x;
    const int wv   = tid >> 6;
    const int lane = tid & 63;
    const int ptc  = lane & 15;     // MFMA n / m index; gather row owner
    const int qg   = lane >> 4;     // quad group: owns ch qg*8..+7 (+32)
    const int p4   = ptc * 4;

    // ---- weight A-fragments in registers: A[m=lane&15][k=qg*8+j (+32*ks)] ----
    short8 wmF[4][2];
    #pragma unroll
    for (int mt = 0; mt < 4; ++mt)
        #pragma unroll
        for (int ks = 0; ks < 2; ++ks)
            wmF[mt][ks] = *(const short8*)&wmb[(size_t)(mt * 16 + ptc) * CIN + qg * 8 + ks * 32];
    short8 wcF[8][2];
    #pragma unroll
    for (int mt = 0; mt < 8; ++mt)
        #pragma unroll
        for (int ks = 0; ks < 2; ++ks)
            wcF[mt][ks] = *(const short8*)&wcb[(size_t)(mt * 16 + ptc) * CIN + qg * 8 + ks * 32];

    f32x4 acc2[8];
    #pragma unroll
    for (int i = 0; i < 8; ++i) acc2[i] = (f32x4){0.f, 0.f, 0.f, 0.f};

    for (int g = blockIdx.x * 4 + wv; g < BNP / KNB; g += 2048) {
        // group's 256 neighbor indices: lane holds idx flat [4*lane .. 4*lane+3];
        // idx[pt][j] lives in lane p4+(j>>2), elem j&3
        i32x4 iv = *(const i32x4*)(nidx + (size_t)g * 256 + lane * 4);

        // ---- register gather ring, depth 3 ----
        // lane (ptc,qg), row id=idx[ptc][k]:
        //   rb0 = ch qg*8..+7 (b1_0 frag), rb1 = ch 32+qg*8..+7 (b1_1 frag)
        //   svr[mt] = ch 16mt+4qg..+3 (P-inputs, matches MFMA C-layout rows)
        short8 rb0[3], rb1[3];
        u32x2  svr[3][4];
        #pragma unroll
        for (int kk = 0; kk < 3; ++kk) {
            int id = __shfl(iv[kk & 3], p4 + (kk >> 2));
            const unsigned short* gp = fb + (size_t)id * CIN;
            rb0[kk] = *(const short8*)(gp + qg * 8);
            rb1[kk] = *(const short8*)(gp + 32 + qg * 8);
            #pragma unroll
            for (int mt = 0; mt < 4; ++mt)
                svr[kk][mt] = *(const u32x2*)(gp + mt * 16 + qg * 4);
        }

        #pragma unroll
        for (int k = 0; k < KNB; ++k) {
            const int sl = k % 3;                          // static under full unroll

            // ---- phase 1: score^T[d, pt] = Wm x spir^T (B-frags from ring) ----
            short8 b1_0 = rb0[sl];
            short8 b1_1 = rb1[sl];
            f32x4 zero4 = (f32x4){0.f, 0.f, 0.f, 0.f};
            f32x4 a1[4];
            #pragma unroll
            for (int mt = 0; mt < 4; ++mt) {
                f32x4 t0 = __builtin_amdgcn_mfma_f32_16x16x32_bf16(wmF[mt][0], b1_0, zero4, 0, 0, 0);
                a1[mt]   = __builtin_amdgcn_mfma_f32_16x16x32_bf16(wmF[mt][1], b1_1, t0,    0, 0, 0);
            }

            // ---- early rb refill for k+3 (slot free once phase-1 issued) ----
            const unsigned short* gpn = fb;                // dummy init
            bool refill = (k + 3 < KNB);
            if (refill) {
                int id = __shfl(iv[(k + 3) & 3], p4 + ((k + 3) >> 2));
                gpn = fb + (size_t)id * CIN;
                rb0[sl] = *(const short8*)(gpn + qg * 8);
                rb1[sl] = *(const short8*)(gpn + 32 + qg * 8);
            }

            // ---- softmax over d: exp in place + xor16/xor32 ----
            float s = 0.f;
            #pragma unroll
            for (int mt = 0; mt < 4; ++mt)
                #pragma unroll
                for (int r = 0; r < 4; ++r) {
                    float x = __expf(a1[mt][r]);
                    a1[mt][r] = x;
                    s += x;
                }
            s += __shfl_xor(s, 16);
            s += __shfl_xor(s, 32);
            float inv = __builtin_amdgcn_rcpf(s);

            // ---- P = attn (.) spir -> plds (bf16, B-layout staging) ----
            unsigned short* pl = plds[wv];
            #pragma unroll
            for (int mt = 0; mt < 4; ++mt) {
                u32x2 sv = svr[sl][mt];                    // loaded 3 iters ago
                unsigned lo = sv[0], hi = sv[1];
                float p0 = bf2f((unsigned short)lo)         * (a1[mt][0] * inv);
                float p1 = bf2f((unsigned short)(lo >> 16)) * (a1[mt][1] * inv);
                float p2 = bf2f((unsigned short)hi)         * (a1[mt][2] * inv);
                float p3 = bf2f((unsigned short)(hi >> 16)) * (a1[mt][3] * inv);
                unsigned w0 = ((__float_as_uint(p0) + 0x8000u) >> 16) |
                              ((__float_as_uint(p1) + 0x8000u) & 0xFFFF0000u);
                unsigned w1 = ((__float_as_uint(p2) + 0x8000u) >> 16) |
                              ((__float_as_uint(p3) + 0x8000u) & 0xFFFF0000u);
                *(u32x2*)&pl[ptc * 72 + mt * 16 + qg * 4] = (u32x2){w0, w1};
            }

            // ---- late sv refill for k+3 (svr[sl] dead after pack) ----
            if (refill) {
                #pragma unroll
                for (int mt = 0; mt < 4; ++mt)
                    svr[sl][mt] = *(const u32x2*)(gpn + mt * 16 + qg * 4);
            }

            // ---- B2 frags: P[pt=lane&15][d=qg*8+j+32ks] ----
            short8 b2_0 = *(const short8*)&pl[ptc * 72 +      qg * 8];
            short8 b2_1 = *(const short8*)&pl[ptc * 72 + 32 + qg * 8];

            // ---- phase 2: acc2[o,pt] += Wc x P_k (fused pool+linear; AGPRs) ----
            #pragma unroll
            for (int mt = 0; mt < 8; ++mt) {
                acc2[mt] = __builtin_amdgcn_mfma_f32_16x16x32_bf16(wcF[mt][0], b2_0, acc2[mt], 0, 0, 0);
                acc2[mt] = __builtin_amdgcn_mfma_f32_16x16x32_bf16(wcF[mt][1], b2_1, acc2[mt], 0, 0, 0);
            }
        }

        // ---- epilogue: direct C-layout store (R1-proven), b_conv absorbed by BN ----
        int p0 = g * KNB;
        int b  = p0 >> 14;
        int nn = (p0 & (NPTS - 1)) + ptc;
        float* ob = out + (((size_t)b * COUT) << 14) + nn;
        #pragma unroll
        for (int mt = 0; mt < 8; ++mt)
            #pragma unroll
            for (int r = 0; r < 4; ++r) {
                ob[((size_t)(mt * 16 + qg * 4 + r)) << 14] = acc2[mt][r];
                acc2[mt][r] = 0.f;
            }
    }
}

// ---------------- K2: deterministic BN partials, one block per (o, b) ----------------
__global__ __launch_bounds__(256) void k_part(const float* __restrict__ out,
                                              float* __restrict__ part)
{
    int o = blockIdx.x >> 2, b = blockIdx.x & 3;
    const float4* p = (const float4*)(out + (((size_t)(b * COUT + o)) << 14));
    float s = 0.f, q = 0.f;
    for (int i = threadIdx.x; i < NPTS / 4; i += 256) {
        float4 v = p[i];
        s += (v.x + v.y) + (v.z + v.w);
        q += (v.x * v.x + v.y * v.y) + (v.z * v.z + v.w * v.w);
    }
    #pragma unroll
    for (int off = 32; off >= 1; off >>= 1) {
        s += __shfl_xor(s, off);
        q += __shfl_xor(q, off);
    }
    __shared__ float ls[4], lq[4];
    if ((threadIdx.x & 63) == 0) { ls[threadIdx.x >> 6] = s; lq[threadIdx.x >> 6] = q; }
    __syncthreads();
    if (threadIdx.x == 0) {
        part[blockIdx.x * 2]     = (ls[0] + ls[1]) + (ls[2] + ls[3]);
        part[blockIdx.x * 2 + 1] = (lq[0] + lq[1]) + (lq[2] + lq[3]);
    }
}

// ---------------- K3: finalize stats per block + apply BN in place ----------------
__global__ __launch_bounds__(256) void k_apply(float* __restrict__ out,
                                               const float* __restrict__ part,
                                               const float* __restrict__ gamma,
                                               const float* __restrict__ beta)
{
    __shared__ float sc[COUT], sh[COUT];
    int t = threadIdx.x;
    if (t < COUT) {
        float s = 0.f, q = 0.f;
        #pragma unroll
        for (int j = 0; j < 4; ++j) {
            s += part[(t * 4 + j) * 2];
            q += part[(t * 4 + j) * 2 + 1];
        }
        float mean = s * (1.0f / BNP);
        float var  = q * (1.0f / BNP) - mean * mean;
        float a = gamma[t] * rsqrtf(var + BN_EPS);
        sc[t] = a; sh[t] = beta[t] - mean * a;
    }
    __syncthreads();
    const int total4 = BATCH * COUT * NPTS / 4;
    for (long i = (long)blockIdx.x * 256 + t; i < total4; i += (long)gridDim.x * 256) {
        int ch = ((int)(i >> 12)) & 127;
        float4 v = ((float4*)out)[i];
        float a = sc[ch], b2 = sh[ch];
        v.x = fmaf(v.x, a, b2); v.y = fmaf(v.y, a, b2);
        v.z = fmaf(v.z, a, b2); v.w = fmaf(v.w, a, b2);
        ((float4*)out)[i] = v;
    }
}

extern "C" void kernel_launch(void* const* d_in, const int* in_sizes, int n_in,
                              void* d_out, int out_size, void* d_ws, size_t ws_size,
                              hipStream_t stream)
{
    const float* feat  = (const float*)d_in[0];
    const int*   nidx  = (const int*)  d_in[1];
    // d_in[2] = permatrix (unused); d_in[5] = b_conv (exactly absorbed by BN)
    const float* Wm    = (const float*)d_in[3];
    const float* Wc    = (const float*)d_in[4];
    const float* gamma = (const float*)d_in[6];
    const float* beta  = (const float*)d_in[7];
    float* out = (float*)d_out;

    char* ws = (char*)d_ws;
    unsigned short* fb   = (unsigned short*)ws;                       // 8.39 MB
    float*          part = (float*)(ws + (size_t)BNP * CIN * 2);      // 4 KB
    unsigned short* wmb  = (unsigned short*)(ws + (size_t)BNP * CIN * 2 + 4096);
    unsigned short* wcb  = wmb + CIN * CIN;                           // 8 KB + 16 KB

    k_prep <<<1025, 256, 0, stream>>>(feat, fb, Wm, Wc, wmb, wcb);
    k_main <<<512,  256, 0, stream>>>(fb, nidx, wmb, wcb, out);
    k_part <<<512,  256, 0, stream>>>(out, part);
    k_apply<<<2048, 256, 0, stream>>>(out, part, gamma, beta);
}

// Round 17
// 158.581 us; speedup vs baseline: 2.2823x; 1.0183x over previous
//
#include <hip/hip_runtime.h>
#include <cstdint>

#define NPTS   16384
#define BATCH  4
#define BNP    65536
#define CIN    64
#define KNB    16
#define COUT   128
#define BN_EPS 1e-5f

typedef __attribute__((ext_vector_type(8))) short     short8;
typedef __attribute__((ext_vector_type(4))) float     f32x4;
typedef __attribute__((ext_vector_type(2))) unsigned  u32x2;
typedef __attribute__((ext_vector_type(4))) int       i32x4;

__device__ __forceinline__ unsigned short f2bf(float f) {   // RNE
    unsigned u = __float_as_uint(f);
    u += 0x7FFFu + ((u >> 16) & 1u);
    return (unsigned short)(u >> 16);
}
__device__ __forceinline__ float bf2f(unsigned short h) {
    return __uint_as_float(((unsigned)h) << 16);
}

// ---- K0: feature [B][C][N] -> flat bf16 [B*N][64]; blk 1024: weight cvt ----
// float4 read side (R16); LDS-write 2-way max (free); transpose write unchanged.
__global__ __launch_bounds__(256) void k_prep(const float* __restrict__ feat,
                                              unsigned short* __restrict__ fb,
                                              const float* __restrict__ Wm,
                                              const float* __restrict__ Wc,
                                              unsigned short* __restrict__ wmb,
                                              unsigned short* __restrict__ wcb)
{
    if (blockIdx.x == 1024) {           // aux block: bf16-ify weights
        #pragma unroll
        for (int i = threadIdx.x; i < CIN * CIN; i += 256)       wmb[i] = f2bf(Wm[i]);
        #pragma unroll
        for (int i = threadIdx.x; i < COUT * CIN; i += 256)      wcb[i] = f2bf(Wc[i]);
        return;
    }
    __shared__ float t[CIN][CIN + 1];
    int blk = blockIdx.x;
    int b   = blk >> 8;
    int n0  = (blk & 255) << 6;
    int c   = threadIdx.x >> 2;                            // 0..63: source channel row
    int q   = threadIdx.x & 3;                             // quarter of the 64-pt row
    const float* fp = feat + (size_t)b * CIN * NPTS + (size_t)c * NPTS + n0 + q * 16;
    #pragma unroll
    for (int j = 0; j < 4; ++j) {
        float4 v = *(const float4*)(fp + j * 4);
        int o = q * 16 + j * 4;
        t[c][o]     = v.x;
        t[c][o + 1] = v.y;
        t[c][o + 2] = v.z;
        t[c][o + 3] = v.w;
    }
    __syncthreads();
    int sub = threadIdx.x >> 6, lane = threadIdx.x & 63;
    unsigned short* ob = fb + (size_t)(b * NPTS + n0) * CIN;
    #pragma unroll
    for (int r = 0; r < CIN; r += 4) {
        int x = r + sub;
        ob[(size_t)x * CIN + lane] = f2bf(t[lane][x]);     // row n0+x, ch=lane
    }
}

// ---------------- K1: gather+attention+linear -- R7/R16 body + T5 setprio --------------
// R16 verified codegen (VGPR 116 / SGPR 48 / LDS 9216, k_main 62.4-63.7us).
// Round-17 single variable: s_setprio(1) around both MFMA clusters (T5). Mechanism:
// 8 waves/CU, NO barriers, waves at different phases -> CU scheduler arbitration has
// room (the m191 attn regime, +4-7%), unlike barrier-locked GEMM (m190 null).
// Do NOT touch: pool-first (R2/4 spill), global_load_lds (R5 vmcnt drain), grid 1024
// (R8 null: reg-capped 2 waves/SIMD), k-pair ILP (R10 null), coop fusion (R15 -100us),
// lane-atomics on packed stats (R13 -400us).
__global__ __launch_bounds__(256, 2) void k_main(
    const unsigned short* __restrict__ fb,   // [BNP][64] bf16
    const int* __restrict__ nidx,            // [BNP][16]
    const unsigned short* __restrict__ wmb,  // [64][64] bf16
    const unsigned short* __restrict__ wcb,  // [128][64] bf16
    float* __restrict__ out)                 // [4][128][16384], pre-BN
{
    __shared__ __align__(16) unsigned short plds[4][1152];   // 9.2 KB, wave-private

    const int tid  = threadIdx.x;
    const int wv   = tid >> 6;
    const int lane = tid & 63;
    const int ptc  = lane & 15;     // MFMA n / m index; gather row owner
    const int qg   = lane >> 4;     // quad group: owns ch qg*8..+7 (+32)
    const int p4   = ptc * 4;

    // ---- weight A-fragments in registers: A[m=lane&15][k=qg*8+j (+32*ks)] ----
    short8 wmF[4][2];
    #pragma unroll
    for (int mt = 0; mt < 4; ++mt)
        #pragma unroll
        for (int ks = 0; ks < 2; ++ks)
            wmF[mt][ks] = *(const short8*)&wmb[(size_t)(mt * 16 + ptc) * CIN + qg * 8 + ks * 32];
    short8 wcF[8][2];
    #pragma unroll
    for (int mt = 0; mt < 8; ++mt)
        #pragma unroll
        for (int ks = 0; ks < 2; ++ks)
            wcF[mt][ks] = *(const short8*)&wcb[(size_t)(mt * 16 + ptc) * CIN + qg * 8 + ks * 32];

    f32x4 acc2[8];
    #pragma unroll
    for (int i = 0; i < 8; ++i) acc2[i] = (f32x4){0.f, 0.f, 0.f, 0.f};

    for (int g = blockIdx.x * 4 + wv; g < BNP / KNB; g += 2048) {
        // group's 256 neighbor indices: lane holds idx flat [4*lane .. 4*lane+3];
        // idx[pt][j] lives in lane p4+(j>>2), elem j&3
        i32x4 iv = *(const i32x4*)(nidx + (size_t)g * 256 + lane * 4);

        // ---- register gather ring, depth 3 ----
        // lane (ptc,qg), row id=idx[ptc][k]:
        //   rb0 = ch qg*8..+7 (b1_0 frag), rb1 = ch 32+qg*8..+7 (b1_1 frag)
        //   svr[mt] = ch 16mt+4qg..+3 (P-inputs, matches MFMA C-layout rows)
        short8 rb0[3], rb1[3];
        u32x2  svr[3][4];
        #pragma unroll
        for (int kk = 0; kk < 3; ++kk) {
            int id = __shfl(iv[kk & 3], p4 + (kk >> 2));
            const unsigned short* gp = fb + (size_t)id * CIN;
            rb0[kk] = *(const short8*)(gp + qg * 8);
            rb1[kk] = *(const short8*)(gp + 32 + qg * 8);
            #pragma unroll
            for (int mt = 0; mt < 4; ++mt)
                svr[kk][mt] = *(const u32x2*)(gp + mt * 16 + qg * 4);
        }

        #pragma unroll
        for (int k = 0; k < KNB; ++k) {
            const int sl = k % 3;                          // static under full unroll

            // ---- phase 1: score^T[d, pt] = Wm x spir^T (B-frags from ring) ----
            short8 b1_0 = rb0[sl];
            short8 b1_1 = rb1[sl];
            f32x4 zero4 = (f32x4){0.f, 0.f, 0.f, 0.f};
            f32x4 a1[4];
            __builtin_amdgcn_s_setprio(1);                 // T5: favor MFMA wave
            #pragma unroll
            for (int mt = 0; mt < 4; ++mt) {
                f32x4 t0 = __builtin_amdgcn_mfma_f32_16x16x32_bf16(wmF[mt][0], b1_0, zero4, 0, 0, 0);
                a1[mt]   = __builtin_amdgcn_mfma_f32_16x16x32_bf16(wmF[mt][1], b1_1, t0,    0, 0, 0);
            }
            __builtin_amdgcn_s_setprio(0);

            // ---- early rb refill for k+3 (slot free once phase-1 issued) ----
            const unsigned short* gpn = fb;                // dummy init
            bool refill = (k + 3 < KNB);
            if (refill) {
                int id = __shfl(iv[(k + 3) & 3], p4 + ((k + 3) >> 2));
                gpn = fb + (size_t)id * CIN;
                rb0[sl] = *(const short8*)(gpn + qg * 8);
                rb1[sl] = *(const short8*)(gpn + 32 + qg * 8);
            }

            // ---- softmax over d: exp in place + xor16/xor32 ----
            float s = 0.f;
            #pragma unroll
            for (int mt = 0; mt < 4; ++mt)
                #pragma unroll
                for (int r = 0; r < 4; ++r) {
                    float x = __expf(a1[mt][r]);
                    a1[mt][r] = x;
                    s += x;
                }
            s += __shfl_xor(s, 16);
            s += __shfl_xor(s, 32);
            float inv = __builtin_amdgcn_rcpf(s);

            // ---- P = attn (.) spir -> plds (bf16, B-layout staging) ----
            unsigned short* pl = plds[wv];
            #pragma unroll
            for (int mt = 0; mt < 4; ++mt) {
                u32x2 sv = svr[sl][mt];                    // loaded 3 iters ago
                unsigned lo = sv[0], hi = sv[1];
                float p0 = bf2f((unsigned short)lo)         * (a1[mt][0] * inv);
                float p1 = bf2f((unsigned short)(lo >> 16)) * (a1[mt][1] * inv);
                float p2 = bf2f((unsigned short)hi)         * (a1[mt][2] * inv);
                float p3 = bf2f((unsigned short)(hi >> 16)) * (a1[mt][3] * inv);
                unsigned w0 = ((__float_as_uint(p0) + 0x8000u) >> 16) |
                              ((__float_as_uint(p1) + 0x8000u) & 0xFFFF0000u);
                unsigned w1 = ((__float_as_uint(p2) + 0x8000u) >> 16) |
                              ((__float_as_uint(p3) + 0x8000u) & 0xFFFF0000u);
                *(u32x2*)&pl[ptc * 72 + mt * 16 + qg * 4] = (u32x2){w0, w1};
            }

            // ---- late sv refill for k+3 (svr[sl] dead after pack) ----
            if (refill) {
                #pragma unroll
                for (int mt = 0; mt < 4; ++mt)
                    svr[sl][mt] = *(const u32x2*)(gpn + mt * 16 + qg * 4);
            }

            // ---- B2 frags: P[pt=lane&15][d=qg*8+j+32ks] ----
            short8 b2_0 = *(const short8*)&pl[ptc * 72 +      qg * 8];
            short8 b2_1 = *(const short8*)&pl[ptc * 72 + 32 + qg * 8];

            // ---- phase 2: acc2[o,pt] += Wc x P_k (fused pool+linear; AGPRs) ----
            __builtin_amdgcn_s_setprio(1);                 // T5: favor MFMA wave
            #pragma unroll
            for (int mt = 0; mt < 8; ++mt) {
                acc2[mt] = __builtin_amdgcn_mfma_f32_16x16x32_bf16(wcF[mt][0], b2_0, acc2[mt], 0, 0, 0);
                acc2[mt] = __builtin_amdgcn_mfma_f32_16x16x32_bf16(wcF[mt][1], b2_1, acc2[mt], 0, 0, 0);
            }
            __builtin_amdgcn_s_setprio(0);
        }

        // ---- epilogue: direct C-layout store (R1-proven), b_conv absorbed by BN ----
        int p0 = g * KNB;
        int b  = p0 >> 14;
        int nn = (p0 & (NPTS - 1)) + ptc;
        float* ob = out + (((size_t)b * COUT) << 14) + nn;
        #pragma unroll
        for (int mt = 0; mt < 8; ++mt)
            #pragma unroll
            for (int r = 0; r < 4; ++r) {
                ob[((size_t)(mt * 16 + qg * 4 + r)) << 14] = acc2[mt][r];
                acc2[mt][r] = 0.f;
            }
    }
}

// ---------------- K2: deterministic BN partials, one block per (o, b) ----------------
__global__ __launch_bounds__(256) void k_part(const float* __restrict__ out,
                                              float* __restrict__ part)
{
    int o = blockIdx.x >> 2, b = blockIdx.x & 3;
    const float4* p = (const float4*)(out + (((size_t)(b * COUT + o)) << 14));
    float s = 0.f, q = 0.f;
    for (int i = threadIdx.x; i < NPTS / 4; i += 256) {
        float4 v = p[i];
        s += (v.x + v.y) + (v.z + v.w);
        q += (v.x * v.x + v.y * v.y) + (v.z * v.z + v.w * v.w);
    }
    #pragma unroll
    for (int off = 32; off >= 1; off >>= 1) {
        s += __shfl_xor(s, off);
        q += __shfl_xor(q, off);
    }
    __shared__ float ls[4], lq[4];
    if ((threadIdx.x & 63) == 0) { ls[threadIdx.x >> 6] = s; lq[threadIdx.x >> 6] = q; }
    __syncthreads();
    if (threadIdx.x == 0) {
        part[blockIdx.x * 2]     = (ls[0] + ls[1]) + (ls[2] + ls[3]);
        part[blockIdx.x * 2 + 1] = (lq[0] + lq[1]) + (lq[2] + lq[3]);
    }
}

// ---------------- K3: finalize stats per block + apply BN in place ----------------
__global__ __launch_bounds__(256) void k_apply(float* __restrict__ out,
                                               const float* __restrict__ part,
                                               const float* __restrict__ gamma,
                                               const float* __restrict__ beta)
{
    __shared__ float sc[COUT], sh[COUT];
    int t = threadIdx.x;
    if (t < COUT) {
        float s = 0.f, q = 0.f;
        #pragma unroll
        for (int j = 0; j < 4; ++j) {
            s += part[(t * 4 + j) * 2];
            q += part[(t * 4 + j) * 2 + 1];
        }
        float mean = s * (1.0f / BNP);
        float var  = q * (1.0f / BNP) - mean * mean;
        float a = gamma[t] * rsqrtf(var + BN_EPS);
        sc[t] = a; sh[t] = beta[t] - mean * a;
    }
    __syncthreads();
    const int total4 = BATCH * COUT * NPTS / 4;
    for (long i = (long)blockIdx.x * 256 + t; i < total4; i += (long)gridDim.x * 256) {
        int ch = ((int)(i >> 12)) & 127;
        float4 v = ((float4*)out)[i];
        float a = sc[ch], b2 = sh[ch];
        v.x = fmaf(v.x, a, b2); v.y = fmaf(v.y, a, b2);
        v.z = fmaf(v.z, a, b2); v.w = fmaf(v.w, a, b2);
        ((float4*)out)[i] = v;
    }
}

extern "C" void kernel_launch(void* const* d_in, const int* in_sizes, int n_in,
                              void* d_out, int out_size, void* d_ws, size_t ws_size,
                              hipStream_t stream)
{
    const float* feat  = (const float*)d_in[0];
    const int*   nidx  = (const int*)  d_in[1];
    // d_in[2] = permatrix (unused); d_in[5] = b_conv (exactly absorbed by BN)
    const float* Wm    = (const float*)d_in[3];
    const float* Wc    = (const float*)d_in[4];
    const float* gamma = (const float*)d_in[6];
    const float* beta  = (const float*)d_in[7];
    float* out = (float*)d_out;

    char* ws = (char*)d_ws;
    unsigned short* fb   = (unsigned short*)ws;                       // 8.39 MB
    float*          part = (float*)(ws + (size_t)BNP * CIN * 2);      // 4 KB
    unsigned short* wmb  = (unsigned short*)(ws + (size_t)BNP * CIN * 2 + 4096);
    unsigned short* wcb  = wmb + CIN * CIN;                           // 8 KB + 16 KB

    k_prep <<<1025, 256, 0, stream>>>(feat, fb, Wm, Wc, wmb, wcb);
    k_main <<<512,  256, 0, stream>>>(fb, nidx, wmb, wcb, out);
    k_part <<<512,  256, 0, stream>>>(out, part);
    k_apply<<<2048, 256, 0, stream>>>(out, part, gamma, beta);
}